// Round 1
// baseline (916.192 us; speedup 1.0000x reference)
//
#include <hip/hip_runtime.h>
#include <math.h>

// Problem constants
#define B_    512
#define T_    256
#define DIN   64
#define DS    64
#define KK    128   // DIN + DS
#define NN    2048
#define DOUT  10

// Tiling: 128 WGs = NTILES(4) x BTILES(32); each WG runs TWO independent
// 8-row cohorts (A: rows bt*16.., B: rows bt*16+8..) interleaved per step
// so each cohort's exchange RTT hides under the other cohort's compute.
#define NT      512
#define BT      8                 // rows per cohort
#define NTILES  (NN / NT)         // 4
#define BTE     (B_ / BT)         // 64 cohort slots (psq bt_eff dimension)
#define BTILES  (BTE / 2)         // 32 workgroup b-tiles
#define THREADS 512
#define NWG     (NTILES * BTILES) // 128

// Workspace: psq (u64 tagged partials, double-buffered) | EtSw | SdSw
#define PSQ_ELEMS  ((size_t)BTE * NTILES * BT * DS)  // 131072 u64 per buffer
#define PS_FLOATS  (4 * PSQ_ELEMS)                   // 2 buffers as float count
#define ETSW_OFF   PS_FLOATS
#define ETSW_F16   ((size_t)KK * NN)                 // 262144 f16 = 512 KB
#define SDSW_OFF   (ETSW_OFF + ETSW_F16 / 2)
#define SDSW_F16   ((size_t)NN * DS)                 // 131072 f16 = 256 KB

typedef _Float16 half8 __attribute__((ext_vector_type(8)));
typedef float    f32x4 __attribute__((ext_vector_type(4)));

__global__ __launch_bounds__(256) void pre_kernel(const float* __restrict__ enc,
                                                  const float* __restrict__ sd,
                                                  float* __restrict__ ws,
                                                  float* __restrict__ out) {
    size_t i = (size_t)blockIdx.x * blockDim.x + threadIdx.x;
    size_t stride = (size_t)gridDim.x * blockDim.x;
    // zero tagged-partial buffers (tag 0 never matches: consumer tags >= 1)
    unsigned long long* psq = (unsigned long long*)ws;
    for (size_t x = i; x < 2 * PSQ_ELEMS; x += stride) psq[x] = 0ull;
    // EtSw: B-fragments, 8-wave ownership (R13-verified).
    _Float16* EtSw = (_Float16*)(ws + ETSW_OFF);
    for (size_t x = i; x < (size_t)KK * NN; x += stride) {
        const int j     = (int)(x & 7);
        const int lane  = (int)((x >> 3) & 63);
        const int ktile = (int)((x >> 9) & 3);
        const int ntile = (int)((x >> 11) & 3);
        const int w     = (int)((x >> 13) & 7);
        const int nt    = (int)(x >> 16);
        const int n = nt * 512 + w * 64 + ntile * 16 + (lane & 15);
        const int k = ktile * 32 + ((lane >> 4) << 3) + j;
        EtSw[x] = (_Float16)enc[(size_t)n * KK + k];
    }
    // SdSw: decode B-fragments, FULL-K ownership (R12-verified layout).
    _Float16* SdSw = (_Float16*)(ws + SDSW_OFF);
    for (size_t x = i; x < (size_t)NN * DS; x += stride) {
        const int j     = (int)(x & 7);
        const int lane  = (int)((x >> 3) & 63);
        const int ktile = (int)((x >> 9) & 15);
        const int cg    = (int)((x >> 13) & 3);
        const int nt    = (int)(x >> 15);
        const int n = nt * 512 + ktile * 32 + ((lane >> 4) << 3) + j;
        const int c = cg * 16 + (lane & 15);
        SdSw[x] = (_Float16)sd[(size_t)n * DS + c];
    }
    for (size_t x = i; x < (size_t)B_ * DOUT; x += stride) out[x] = 0.0f;
}

// Two-cohort interleave on top of the R17 tagged-payload core:
//  - cohort A (bt_eff=2*bt) and cohort B (2*bt+1) advance the same t in one
//    loop body; polls are issued a full half-step before their check, and
//    partner stores land a half-step before our issue -> zero-retry steady
//    state, load RTT hidden under the other cohort's decode+encode.
//  - per-cohort structure (fragments, fan-in, tag induction) identical to
//    the verified single-cohort kernel; cohorts share only barriers.
__global__ __launch_bounds__(THREADS, 1) void persist_kernel(
    const float* __restrict__ seq,          // [B][T][DIN]
    const _Float16* __restrict__ EtSw,      // encoder B-fragments
    const _Float16* __restrict__ SdSw,      // state-decoder B-fragments
    const float* __restrict__ bias,
    const float* __restrict__ gain,
    const float* __restrict__ dec,          // [NN][DOUT]
    unsigned long long* __restrict__ psq,   // [2][BTE][NTILES][BT][DS] tagged
    float* __restrict__ out)
{
    __shared__ _Float16 xhA[16][136];   // cohort A x_aug (rows 8..15 zero)
    __shared__ _Float16 xhB[16][136];   // cohort B x_aug
    __shared__ _Float16 AshA[16][520];  // cohort A activations
    __shared__ _Float16 AshB[16][520];  // cohort B activations

    const int tid = threadIdx.x;
    const int nt = blockIdx.x & (NTILES - 1);
    const int bt = blockIdx.x >> 2;        // 0..31
    const int n0 = nt * NT;
    const int beA = bt * 2;                // psq slot, cohort A
    const int beB = bt * 2 + 1;            // psq slot, cohort B
    const int b0A = bt * 16;
    const int b0B = bt * 16 + 8;

    const int w = tid >> 6;            // wave 0..7
    const int l = tid & 63;
    const int rs = tid >> 6;           // fan-in row 0..7
    const int cs = tid & 63;           // fan-in col
    const int m16 = l & 15;            // fragment row/col index
    const int q8  = (l >> 4) << 3;     // fragment k sub-offset

    const _Float16* EtW = EtSw + ((size_t)(nt * 8 + w) << 13);
    const _Float16* SdW = SdSw + ((size_t)(nt * 4 + (w & 3)) << 13);

    // ---- register-resident weight fragments (loaded once) ----
    half8 etf[4][4];   // [ntile][ktile]
    #pragma unroll
    for (int n4 = 0; n4 < 4; ++n4)
        #pragma unroll
        for (int kt = 0; kt < 4; ++kt)
            etf[n4][kt] = *(const half8*)&EtW[(n4 << 11) + (kt << 9) + (size_t)l * 8];
    half8 sdf[16];     // full-K decode fragments (used by waves 0..3)
    #pragma unroll
    for (int kt = 0; kt < 16; ++kt)
        sdf[kt] = *(const half8*)&SdW[(kt << 9) + (size_t)l * 8];

    // epilogue params
    float gv[4], bv[4];
    #pragma unroll
    for (int n4 = 0; n4 < 4; ++n4) {
        gv[n4] = gain[n0 + w * 64 + n4 * 16 + m16];
        bv[n4] = bias[n0 + w * 64 + n4 * 16 + m16];
    }

    // fan-in bases: this thread's 4 partials per cohort, stride BT*DS u64s
    const size_t fanA = ((size_t)beA * NTILES) * BT * DS + (size_t)rs * DS + cs;
    const size_t fanB = ((size_t)beB * NTILES) * BT * DS + (size_t)rs * DS + cs;

    // preamble: zero xhA/xhB (rows 8..15 stay zero), stage u_0 both cohorts
    {
        unsigned int* xz = (unsigned int*)&xhA[0][0];
        for (int i2 = tid; i2 < 16 * 136 / 2; i2 += THREADS) xz[i2] = 0u;
        unsigned int* xz2 = (unsigned int*)&xhB[0][0];
        for (int i2 = tid; i2 < 16 * 136 / 2; i2 += THREADS) xz2[i2] = 0u;
    }
    __syncthreads();
    if (tid < 256) {
        const int ch  = tid >> 7;
        const int idx = tid & 127;
        const int r = idx >> 4, c = (idx & 15) << 2;
        const float4 uv =
            *(const float4*)&seq[((size_t)((ch ? b0B : b0A) + r) * T_ + 0) * DIN + c];
        _Float16* p = ch ? &xhB[r][c] : &xhA[r][c];
        p[0] = (_Float16)uv.x; p[1] = (_Float16)uv.y;
        p[2] = (_Float16)uv.z; p[3] = (_Float16)uv.w;
    }
    __syncthreads();

    unsigned long long vA0 = 0, vA1 = 0, vA2 = 0, vA3 = 0;  // pollA regs
    unsigned long long vB0 = 0, vB1 = 0, vB2 = 0, vB3 = 0;  // pollB regs

    for (int t = 0; t < T_; ++t) {
        // ==================== cohort A half-step ====================
        f32x4 acc[4];
        #pragma unroll
        for (int n4 = 0; n4 < 4; ++n4) acc[n4] = (f32x4){0.f, 0.f, 0.f, 0.f};
        {   // encode phase A: k-tiles 0,1 (u_t only; no barrier needed)
            const half8 af0 = *(const half8*)&xhA[m16][q8];
            const half8 af1 = *(const half8*)&xhA[m16][32 + q8];
            #pragma unroll
            for (int n4 = 0; n4 < 4; ++n4) {
                acc[n4] = __builtin_amdgcn_mfma_f32_16x16x32_f16(af0, etf[n4][0], acc[n4], 0, 0, 0);
                acc[n4] = __builtin_amdgcn_mfma_f32_16x16x32_f16(af1, etf[n4][1], acc[n4], 0, 0, 0);
            }
        }
        // acquire sA(t-1): vA* issued last iteration (after decodeB)
        if (t > 0) {
            const unsigned long long* pbA =
                psq + (size_t)((t - 1) & 1) * PSQ_ELEMS + fanA;
            const unsigned utag = (unsigned)t;
            for (;;) {
                if ((unsigned)(vA0 >> 32) == utag && (unsigned)(vA1 >> 32) == utag &&
                    (unsigned)(vA2 >> 32) == utag && (unsigned)(vA3 >> 32) == utag)
                    break;
                vA0 = __hip_atomic_load(pbA + 0 * (BT * DS), __ATOMIC_RELAXED, __HIP_MEMORY_SCOPE_AGENT);
                vA1 = __hip_atomic_load(pbA + 1 * (BT * DS), __ATOMIC_RELAXED, __HIP_MEMORY_SCOPE_AGENT);
                vA2 = __hip_atomic_load(pbA + 2 * (BT * DS), __ATOMIC_RELAXED, __HIP_MEMORY_SCOPE_AGENT);
                vA3 = __hip_atomic_load(pbA + 3 * (BT * DS), __ATOMIC_RELAXED, __HIP_MEMORY_SCOPE_AGENT);
            }
            const float ssum = __uint_as_float((unsigned)vA0) + __uint_as_float((unsigned)vA1)
                             + __uint_as_float((unsigned)vA2) + __uint_as_float((unsigned)vA3);
            xhA[rs][DIN + cs] = (_Float16)ssum;
        } else {
            xhA[rs][DIN + cs] = (_Float16)0.f;
        }
        __syncthreads();   // B1: A state half ready

        {   // encode phase B: k-tiles 2,3
            const half8 af2 = *(const half8*)&xhA[m16][64 + q8];
            const half8 af3 = *(const half8*)&xhA[m16][96 + q8];
            #pragma unroll
            for (int n4 = 0; n4 < 4; ++n4) {
                acc[n4] = __builtin_amdgcn_mfma_f32_16x16x32_f16(af2, etf[n4][2], acc[n4], 0, 0, 0);
                acc[n4] = __builtin_amdgcn_mfma_f32_16x16x32_f16(af3, etf[n4][3], acc[n4], 0, 0, 0);
            }
        }
        // epilogue: rows 0..7 live in lanes 0..31 (row=(l>>4)*4+reg)
        if (l < 32) {
            const int rq = (l >> 4) << 2;
            #pragma unroll
            for (int n4 = 0; n4 < 4; ++n4) {
                const int n = w * 64 + n4 * 16 + m16;
                AshA[rq + 0][n] = (_Float16)fabsf(gv[n4] * acc[n4][0] + bv[n4]);
                AshA[rq + 1][n] = (_Float16)fabsf(gv[n4] * acc[n4][1] + bv[n4]);
                AshA[rq + 2][n] = (_Float16)fabsf(gv[n4] * acc[n4][2] + bv[n4]);
                AshA[rq + 3][n] = (_Float16)fabsf(gv[n4] * acc[n4][3] + bv[n4]);
            }
        }
        __syncthreads();   // B2: AshA ready

        // speculative pollB(t) issue — partner stored B(t-1) a full
        // half-step ago; check happens after decodeA + barrier + encB-A.
        if (t > 0) {
            const unsigned long long* pbB =
                psq + (size_t)((t - 1) & 1) * PSQ_ELEMS + fanB;
            vB0 = __hip_atomic_load(pbB + 0 * (BT * DS), __ATOMIC_RELAXED, __HIP_MEMORY_SCOPE_AGENT);
            vB1 = __hip_atomic_load(pbB + 1 * (BT * DS), __ATOMIC_RELAXED, __HIP_MEMORY_SCOPE_AGENT);
            vB2 = __hip_atomic_load(pbB + 2 * (BT * DS), __ATOMIC_RELAXED, __HIP_MEMORY_SCOPE_AGENT);
            vB3 = __hip_atomic_load(pbB + 3 * (BT * DS), __ATOMIC_RELAXED, __HIP_MEMORY_SCOPE_AGENT);
        }

        if (t == T_ - 1) {
            // final projection, cohort A
            for (int idx = tid; idx < BT * DOUT; idx += THREADS) {
                const int r = idx / DOUT;
                const int d = idx % DOUT;
                float o = 0.f;
                #pragma unroll 8
                for (int n = 0; n < NT; ++n)
                    o += (float)AshA[r][n] * dec[(size_t)(n0 + n) * DOUT + d];
                atomicAdd(&out[(size_t)(b0A + r) * DOUT + d], o);
            }
        } else {
            if (w < 4) {
                // decode A (full K=512)
                f32x4 d0 = (f32x4){0.f, 0.f, 0.f, 0.f};
                f32x4 d1 = (f32x4){0.f, 0.f, 0.f, 0.f};
                #pragma unroll
                for (int kt = 0; kt < 16; kt += 2) {
                    const half8 a0 = *(const half8*)&AshA[m16][kt * 32 + q8];
                    d0 = __builtin_amdgcn_mfma_f32_16x16x32_f16(a0, sdf[kt], d0, 0, 0, 0);
                    const half8 a1 = *(const half8*)&AshA[m16][(kt + 1) * 32 + q8];
                    d1 = __builtin_amdgcn_mfma_f32_16x16x32_f16(a1, sdf[kt + 1], d1, 0, 0, 0);
                }
                d0[0] += d1[0]; d0[1] += d1[1]; d0[2] += d1[2]; d0[3] += d1[3];
                if (l < 32) {
                    const int rq = (l >> 4) << 2;
                    unsigned long long* pw = psq + (size_t)(t & 1) * PSQ_ELEMS
                        + (((size_t)beA * NTILES + nt) * BT) * DS + 16 * w + m16;
                    const unsigned long long tg = (unsigned long long)(unsigned)(t + 1) << 32;
                    #pragma unroll
                    for (int r = 0; r < 4; ++r) {
                        __hip_atomic_store(pw + (size_t)(rq + r) * DS,
                                           tg | (unsigned long long)__float_as_uint(d0[r]),
                                           __ATOMIC_RELAXED, __HIP_MEMORY_SCOPE_AGENT);
                    }
                }
            } else if (l < 32) {
                // stage uA(t+1): 4 waves x 32 lanes = 128 float4 loads
                const int idx = ((w - 4) << 5) + l;
                const int r = idx >> 4, c = (idx & 15) << 2;
                const float4 uv =
                    *(const float4*)&seq[((size_t)(b0A + r) * T_ + (t + 1)) * DIN + c];
                _Float16* p = &xhA[r][c];
                p[0] = (_Float16)uv.x; p[1] = (_Float16)uv.y;
                p[2] = (_Float16)uv.z; p[3] = (_Float16)uv.w;
            }
        }
        __syncthreads();   // B3: AshA reads done + uA staged

        // ==================== cohort B half-step ====================
        #pragma unroll
        for (int n4 = 0; n4 < 4; ++n4) acc[n4] = (f32x4){0.f, 0.f, 0.f, 0.f};
        {   // encode phase A
            const half8 af0 = *(const half8*)&xhB[m16][q8];
            const half8 af1 = *(const half8*)&xhB[m16][32 + q8];
            #pragma unroll
            for (int n4 = 0; n4 < 4; ++n4) {
                acc[n4] = __builtin_amdgcn_mfma_f32_16x16x32_f16(af0, etf[n4][0], acc[n4], 0, 0, 0);
                acc[n4] = __builtin_amdgcn_mfma_f32_16x16x32_f16(af1, etf[n4][1], acc[n4], 0, 0, 0);
            }
        }
        // acquire sB(t-1)
        if (t > 0) {
            const unsigned long long* pbB =
                psq + (size_t)((t - 1) & 1) * PSQ_ELEMS + fanB;
            const unsigned utag = (unsigned)t;
            for (;;) {
                if ((unsigned)(vB0 >> 32) == utag && (unsigned)(vB1 >> 32) == utag &&
                    (unsigned)(vB2 >> 32) == utag && (unsigned)(vB3 >> 32) == utag)
                    break;
                vB0 = __hip_atomic_load(pbB + 0 * (BT * DS), __ATOMIC_RELAXED, __HIP_MEMORY_SCOPE_AGENT);
                vB1 = __hip_atomic_load(pbB + 1 * (BT * DS), __ATOMIC_RELAXED, __HIP_MEMORY_SCOPE_AGENT);
                vB2 = __hip_atomic_load(pbB + 2 * (BT * DS), __ATOMIC_RELAXED, __HIP_MEMORY_SCOPE_AGENT);
                vB3 = __hip_atomic_load(pbB + 3 * (BT * DS), __ATOMIC_RELAXED, __HIP_MEMORY_SCOPE_AGENT);
            }
            const float ssum = __uint_as_float((unsigned)vB0) + __uint_as_float((unsigned)vB1)
                             + __uint_as_float((unsigned)vB2) + __uint_as_float((unsigned)vB3);
            xhB[rs][DIN + cs] = (_Float16)ssum;
        } else {
            xhB[rs][DIN + cs] = (_Float16)0.f;
        }
        __syncthreads();   // B4: B state half ready

        {   // encode phase B
            const half8 af2 = *(const half8*)&xhB[m16][64 + q8];
            const half8 af3 = *(const half8*)&xhB[m16][96 + q8];
            #pragma unroll
            for (int n4 = 0; n4 < 4; ++n4) {
                acc[n4] = __builtin_amdgcn_mfma_f32_16x16x32_f16(af2, etf[n4][2], acc[n4], 0, 0, 0);
                acc[n4] = __builtin_amdgcn_mfma_f32_16x16x32_f16(af3, etf[n4][3], acc[n4], 0, 0, 0);
            }
        }
        if (l < 32) {
            const int rq = (l >> 4) << 2;
            #pragma unroll
            for (int n4 = 0; n4 < 4; ++n4) {
                const int n = w * 64 + n4 * 16 + m16;
                AshB[rq + 0][n] = (_Float16)fabsf(gv[n4] * acc[n4][0] + bv[n4]);
                AshB[rq + 1][n] = (_Float16)fabsf(gv[n4] * acc[n4][1] + bv[n4]);
                AshB[rq + 2][n] = (_Float16)fabsf(gv[n4] * acc[n4][2] + bv[n4]);
                AshB[rq + 3][n] = (_Float16)fabsf(gv[n4] * acc[n4][3] + bv[n4]);
            }
        }
        __syncthreads();   // B5: AshB ready

        if (t == T_ - 1) {
            // final projection, cohort B
            for (int idx = tid; idx < BT * DOUT; idx += THREADS) {
                const int r = idx / DOUT;
                const int d = idx % DOUT;
                float o = 0.f;
                #pragma unroll 8
                for (int n = 0; n < NT; ++n)
                    o += (float)AshB[r][n] * dec[(size_t)(n0 + n) * DOUT + d];
                atomicAdd(&out[(size_t)(b0B + r) * DOUT + d], o);
            }
        } else {
            // speculative pollA(t+1) issue — partner stored A(t) in its
            // first half-step; check happens after decodeB + B6 + encA-A.
            const unsigned long long* pbA =
                psq + (size_t)(t & 1) * PSQ_ELEMS + fanA;
            vA0 = __hip_atomic_load(pbA + 0 * (BT * DS), __ATOMIC_RELAXED, __HIP_MEMORY_SCOPE_AGENT);
            vA1 = __hip_atomic_load(pbA + 1 * (BT * DS), __ATOMIC_RELAXED, __HIP_MEMORY_SCOPE_AGENT);
            vA2 = __hip_atomic_load(pbA + 2 * (BT * DS), __ATOMIC_RELAXED, __HIP_MEMORY_SCOPE_AGENT);
            vA3 = __hip_atomic_load(pbA + 3 * (BT * DS), __ATOMIC_RELAXED, __HIP_MEMORY_SCOPE_AGENT);

            if (w < 4) {
                // decode B (full K=512)
                f32x4 d0 = (f32x4){0.f, 0.f, 0.f, 0.f};
                f32x4 d1 = (f32x4){0.f, 0.f, 0.f, 0.f};
                #pragma unroll
                for (int kt = 0; kt < 16; kt += 2) {
                    const half8 a0 = *(const half8*)&AshB[m16][kt * 32 + q8];
                    d0 = __builtin_amdgcn_mfma_f32_16x16x32_f16(a0, sdf[kt], d0, 0, 0, 0);
                    const half8 a1 = *(const half8*)&AshB[m16][(kt + 1) * 32 + q8];
                    d1 = __builtin_amdgcn_mfma_f32_16x16x32_f16(a1, sdf[kt + 1], d1, 0, 0, 0);
                }
                d0[0] += d1[0]; d0[1] += d1[1]; d0[2] += d1[2]; d0[3] += d1[3];
                if (l < 32) {
                    const int rq = (l >> 4) << 2;
                    unsigned long long* pw = psq + (size_t)(t & 1) * PSQ_ELEMS
                        + (((size_t)beB * NTILES + nt) * BT) * DS + 16 * w + m16;
                    const unsigned long long tg = (unsigned long long)(unsigned)(t + 1) << 32;
                    #pragma unroll
                    for (int r = 0; r < 4; ++r) {
                        __hip_atomic_store(pw + (size_t)(rq + r) * DS,
                                           tg | (unsigned long long)__float_as_uint(d0[r]),
                                           __ATOMIC_RELAXED, __HIP_MEMORY_SCOPE_AGENT);
                    }
                }
            } else if (l < 32) {
                // stage uB(t+1)
                const int idx = ((w - 4) << 5) + l;
                const int r = idx >> 4, c = (idx & 15) << 2;
                const float4 uv =
                    *(const float4*)&seq[((size_t)(b0B + r) * T_ + (t + 1)) * DIN + c];
                _Float16* p = &xhB[r][c];
                p[0] = (_Float16)uv.x; p[1] = (_Float16)uv.y;
                p[2] = (_Float16)uv.z; p[3] = (_Float16)uv.w;
            }
        }
        __syncthreads();   // B6: AshB reads done + uB staged
    }
}

extern "C" void kernel_launch(void* const* d_in, const int* in_sizes, int n_in,
                              void* d_out, int out_size, void* d_ws, size_t ws_size,
                              hipStream_t stream) {
    const float* seq  = (const float*)d_in[0];
    const float* enc  = (const float*)d_in[1];
    const float* bias = (const float*)d_in[2];
    const float* gain = (const float*)d_in[3];
    const float* sd   = (const float*)d_in[4];
    const float* dec  = (const float*)d_in[5];
    float* out = (float*)d_out;
    float* ws  = (float*)d_ws;   // psq[2] (2 MB) | EtSw | SdSw  (~2.8 MB)

    pre_kernel<<<dim3(1024), dim3(256), 0, stream>>>(enc, sd, ws, out);

    unsigned long long* psq = (unsigned long long*)ws;
    const _Float16* EtSw = (const _Float16*)(ws + ETSW_OFF);
    const _Float16* SdSw = (const _Float16*)(ws + SDSW_OFF);

    persist_kernel<<<dim3(NWG), dim3(THREADS), 0, stream>>>(
        seq, EtSw, SdSw, bias, gain, dec, psq, out);
}

// Round 2
// 869.129 us; speedup vs baseline: 1.0541x; 1.0541x over previous
//
#include <hip/hip_runtime.h>
#include <math.h>

// Problem constants
#define B_    512
#define T_    256
#define DIN   64
#define DS    64
#define KK    128   // DIN + DS
#define NN    2048
#define DOUT  10

// Tiling: 256 WGs = NTILES(4) x BTILES(64), 512 thr (8 waves), 1 WG/CU.
// blockIdx -> (bt, nt) is XCD-swizzled: the 4 clique members (same bt,
// nt=0..3) share blockIdx%8, which under SPX round-robin dispatch puts
// them on the SAME XCD -> exchange via sc0 (L1-bypass, L2-coherent) ops.
// Correctness does NOT depend on the mapping: producers dual-store a slow
// agent-scope copy; consumers fall back to it after 8 stale fast polls.
#define NT      512
#define BT      8
#define NTILES  (NN / NT)      // 4
#define BTILES  (B_ / BT)      // 64
#define THREADS 512
#define NWG     (NTILES * BTILES)   // 256

// Workspace: psqF (fast, sc0) | psqS (slow, agent) | EtSw | SdSw
#define PSQ_ELEMS  ((size_t)BTILES * NTILES * BT * DS)  // 131072 u64 per buffer
#define SLOW_OFF_F (4 * PSQ_ELEMS)                      // floats: fast = 2 bufs u64
#define ETSW_OFF   (8 * PSQ_ELEMS)                      // floats
#define ETSW_F16   ((size_t)KK * NN)                    // 262144 f16 = 512 KB
#define SDSW_OFF   (ETSW_OFF + ETSW_F16 / 2)
#define SDSW_F16   ((size_t)NN * DS)                    // 131072 f16 = 256 KB

typedef _Float16 half8 __attribute__((ext_vector_type(8)));
typedef float    f32x4 __attribute__((ext_vector_type(4)));

__device__ __forceinline__ void ld4_sc0(const unsigned long long* p0,
                                        const unsigned long long* p1,
                                        const unsigned long long* p2,
                                        const unsigned long long* p3,
                                        unsigned long long& v0, unsigned long long& v1,
                                        unsigned long long& v2, unsigned long long& v3) {
    asm volatile("global_load_dwordx2 %0, %4, off sc0\n\t"
                 "global_load_dwordx2 %1, %5, off sc0\n\t"
                 "global_load_dwordx2 %2, %6, off sc0\n\t"
                 "global_load_dwordx2 %3, %7, off sc0\n\t"
                 "s_waitcnt vmcnt(0)"
                 : "=&v"(v0), "=&v"(v1), "=&v"(v2), "=&v"(v3)
                 : "v"(p0), "v"(p1), "v"(p2), "v"(p3)
                 : "memory");
}

__global__ __launch_bounds__(256) void pre_kernel(const float* __restrict__ enc,
                                                  const float* __restrict__ sd,
                                                  float* __restrict__ ws,
                                                  float* __restrict__ out) {
    size_t i = (size_t)blockIdx.x * blockDim.x + threadIdx.x;
    size_t stride = (size_t)gridDim.x * blockDim.x;
    // zero BOTH tagged-partial regions (fast + slow); tag 0 never matches
    unsigned long long* psq = (unsigned long long*)ws;
    for (size_t x = i; x < 4 * PSQ_ELEMS; x += stride) psq[x] = 0ull;
    // EtSw: B-fragments, 8-wave ownership (R13-verified).
    _Float16* EtSw = (_Float16*)(ws + ETSW_OFF);
    for (size_t x = i; x < (size_t)KK * NN; x += stride) {
        const int j     = (int)(x & 7);
        const int lane  = (int)((x >> 3) & 63);
        const int ktile = (int)((x >> 9) & 3);
        const int ntile = (int)((x >> 11) & 3);
        const int w     = (int)((x >> 13) & 7);
        const int nt    = (int)(x >> 16);
        const int n = nt * 512 + w * 64 + ntile * 16 + (lane & 15);
        const int k = ktile * 32 + ((lane >> 4) << 3) + j;
        EtSw[x] = (_Float16)enc[(size_t)n * KK + k];
    }
    // SdSw: decode B-fragments, FULL-K ownership (R12-verified layout).
    _Float16* SdSw = (_Float16*)(ws + SDSW_OFF);
    for (size_t x = i; x < (size_t)NN * DS; x += stride) {
        const int j     = (int)(x & 7);
        const int lane  = (int)((x >> 3) & 63);
        const int ktile = (int)((x >> 9) & 15);
        const int cg    = (int)((x >> 13) & 3);
        const int nt    = (int)(x >> 15);
        const int n = nt * 512 + ktile * 32 + ((lane >> 4) << 3) + j;
        const int c = cg * 16 + (lane & 15);
        SdSw[x] = (_Float16)sd[(size_t)n * DS + c];
    }
    for (size_t x = i; x < (size_t)B_ * DOUT; x += stride) out[x] = 0.0f;
}

// R17 core (tagged-payload exchange, 589 us steady) with the exchange path
// moved from agent-scope (L2-bypass, ~1us exposed RTT measured via the
// 2-cohort experiment) to XCD-local L2 (sc0): clique members co-located by
// blockIdx%8 swizzle; sc0 store->load visibility ~150-250cyc. Agent-scope
// slow copy + bounded fast retries keep correctness placement-independent.
__global__ __launch_bounds__(THREADS, 1) void persist_kernel(
    const float* __restrict__ seq,          // [B][T][DIN]
    const _Float16* __restrict__ EtSw,      // encoder B-fragments
    const _Float16* __restrict__ SdSw,      // state-decoder B-fragments
    const float* __restrict__ bias,
    const float* __restrict__ gain,
    const float* __restrict__ dec,          // [NN][DOUT]
    unsigned long long* __restrict__ psqF,  // fast: [2][BTILES][NTILES][BT][DS]
    unsigned long long* __restrict__ psqS,  // slow (agent) copy, same layout
    float* __restrict__ out)
{
    __shared__ _Float16 xh[16][136];  // x_aug f16 (A-operand), rows 8..15 zero
    __shared__ _Float16 Ash[16][520]; // activations f16 (A-operand for decode)

    const int tid = threadIdx.x;
    // XCD-clique swizzle: clique (bt, nt=0..3) shares blockIdx%8.
    const int r8 = blockIdx.x & 7;         // XCD under SPX round-robin
    const int s  = blockIdx.x >> 3;        // 0..31
    const int nt = s & 3;
    const int bt = r8 * 8 + (s >> 2);      // 0..63, bijective
    const int n0 = nt * NT;
    const int b0 = bt * BT;

    const int w = tid >> 6;            // wave 0..7
    const int l = tid & 63;
    const int rs = tid >> 6;           // fan-in row 0..7
    const int cs = tid & 63;           // fan-in col
    const int m16 = l & 15;            // fragment row/col index
    const int q8  = (l >> 4) << 3;     // fragment k sub-offset

    const _Float16* EtW = EtSw + ((size_t)(nt * 8 + w) << 13);
    const _Float16* SdW = SdSw + ((size_t)(nt * 4 + (w & 3)) << 13);

    // ---- register-resident weight fragments (loaded once) ----
    half8 etf[4][4];   // [ntile][ktile]
    #pragma unroll
    for (int n4 = 0; n4 < 4; ++n4)
        #pragma unroll
        for (int kt = 0; kt < 4; ++kt)
            etf[n4][kt] = *(const half8*)&EtW[(n4 << 11) + (kt << 9) + (size_t)l * 8];
    half8 sdf[16];     // full-K decode fragments (used by waves 0..3)
    #pragma unroll
    for (int kt = 0; kt < 16; ++kt)
        sdf[kt] = *(const half8*)&SdW[(kt << 9) + (size_t)l * 8];

    // epilogue params
    float gv[4], bv[4];
    #pragma unroll
    for (int n4 = 0; n4 < 4; ++n4) {
        gv[n4] = gain[n0 + w * 64 + n4 * 16 + m16];
        bv[n4] = bias[n0 + w * 64 + n4 * 16 + m16];
    }

    // fan-in base: this thread's 4 partials (p = 0..3), stride BT*DS u64s
    const size_t fan_base = ((size_t)bt * NTILES) * BT * DS + (size_t)rs * DS + cs;

    // preamble: zero xh (rows 8..15 stay zero), stage u_0
    {
        unsigned int* xz = (unsigned int*)&xh[0][0];
        for (int i2 = tid; i2 < 16 * 136 / 2; i2 += THREADS) xz[i2] = 0u;
    }
    __syncthreads();
    if (tid < 128) {
        const int r = tid >> 4, c = (tid & 15) << 2;
        const float4 uv = *(const float4*)&seq[((size_t)(b0 + r) * T_ + 0) * DIN + c];
        _Float16* p = &xh[r][c];
        p[0] = (_Float16)uv.x; p[1] = (_Float16)uv.y;
        p[2] = (_Float16)uv.z; p[3] = (_Float16)uv.w;
    }
    __syncthreads();

    for (int t = 0; t < T_; ++t) {
        // ---- speculative fast-poll issue: sc0 loads in flight during encode-A ----
        const unsigned long long* pbF =
            psqF + (size_t)((t - 1) & 1) * PSQ_ELEMS + fan_base;
        const unsigned long long* pbS =
            psqS + (size_t)((t - 1) & 1) * PSQ_ELEMS + fan_base;
        unsigned long long v0 = 0, v1 = 0, v2 = 0, v3 = 0;
        if (t > 0) {
            asm volatile("global_load_dwordx2 %0, %4, off sc0\n\t"
                         "global_load_dwordx2 %1, %5, off sc0\n\t"
                         "global_load_dwordx2 %2, %6, off sc0\n\t"
                         "global_load_dwordx2 %3, %7, off sc0"
                         : "=&v"(v0), "=&v"(v1), "=&v"(v2), "=&v"(v3)
                         : "v"(pbF + 0 * (BT * DS)), "v"(pbF + 1 * (BT * DS)),
                           "v"(pbF + 2 * (BT * DS)), "v"(pbF + 3 * (BT * DS))
                         : "memory");
        }

        // ---- encode phase A: k-tiles 0,1 (u_t staged last step; no barrier) ----
        f32x4 acc[4];
        #pragma unroll
        for (int n4 = 0; n4 < 4; ++n4) acc[n4] = (f32x4){0.f, 0.f, 0.f, 0.f};
        {
            const half8 af0 = *(const half8*)&xh[m16][q8];
            const half8 af1 = *(const half8*)&xh[m16][32 + q8];
            #pragma unroll
            for (int n4 = 0; n4 < 4; ++n4) {
                acc[n4] = __builtin_amdgcn_mfma_f32_16x16x32_f16(af0, etf[n4][0], acc[n4], 0, 0, 0);
                acc[n4] = __builtin_amdgcn_mfma_f32_16x16x32_f16(af1, etf[n4][1], acc[n4], 0, 0, 0);
            }
        }

        // ---- acquire s(t-1): fast sc0 path (bounded), agent fallback ----
        if (t > 0) {
            asm volatile("s_waitcnt vmcnt(0)" ::: "memory");
            __builtin_amdgcn_sched_barrier(0);
            const unsigned utag = (unsigned)t;
            int tries = 0;
            bool ok;
            for (;;) {
                ok = ((unsigned)(v0 >> 32) == utag && (unsigned)(v1 >> 32) == utag &&
                      (unsigned)(v2 >> 32) == utag && (unsigned)(v3 >> 32) == utag);
                if (ok || ++tries > 8) break;
                ld4_sc0(pbF + 0 * (BT * DS), pbF + 1 * (BT * DS),
                        pbF + 2 * (BT * DS), pbF + 3 * (BT * DS), v0, v1, v2, v3);
            }
            if (!ok) {
                // placement-independent fallback: agent-scope slow copy
                for (;;) {
                    v0 = __hip_atomic_load(pbS + 0 * (BT * DS), __ATOMIC_RELAXED, __HIP_MEMORY_SCOPE_AGENT);
                    v1 = __hip_atomic_load(pbS + 1 * (BT * DS), __ATOMIC_RELAXED, __HIP_MEMORY_SCOPE_AGENT);
                    v2 = __hip_atomic_load(pbS + 2 * (BT * DS), __ATOMIC_RELAXED, __HIP_MEMORY_SCOPE_AGENT);
                    v3 = __hip_atomic_load(pbS + 3 * (BT * DS), __ATOMIC_RELAXED, __HIP_MEMORY_SCOPE_AGENT);
                    if ((unsigned)(v0 >> 32) == utag && (unsigned)(v1 >> 32) == utag &&
                        (unsigned)(v2 >> 32) == utag && (unsigned)(v3 >> 32) == utag)
                        break;
                }
            }
            const float ssum = __uint_as_float((unsigned)v0) + __uint_as_float((unsigned)v1)
                             + __uint_as_float((unsigned)v2) + __uint_as_float((unsigned)v3);
            xh[rs][DIN + cs] = (_Float16)ssum;
        } else {
            xh[rs][DIN + cs] = (_Float16)0.f;
        }
        __syncthreads();   // B1: state half ready

        // ---- encode phase B: k-tiles 2,3 ----
        {
            const half8 af2 = *(const half8*)&xh[m16][64 + q8];
            const half8 af3 = *(const half8*)&xh[m16][96 + q8];
            #pragma unroll
            for (int n4 = 0; n4 < 4; ++n4) {
                acc[n4] = __builtin_amdgcn_mfma_f32_16x16x32_f16(af2, etf[n4][2], acc[n4], 0, 0, 0);
                acc[n4] = __builtin_amdgcn_mfma_f32_16x16x32_f16(af3, etf[n4][3], acc[n4], 0, 0, 0);
            }
        }

        // ---- epilogue: rows 0..7 live in lanes 0..31 (row=(l>>4)*4+reg) ----
        if (l < 32) {
            const int rq = (l >> 4) << 2;
            #pragma unroll
            for (int n4 = 0; n4 < 4; ++n4) {
                const int n = w * 64 + n4 * 16 + m16;
                Ash[rq + 0][n] = (_Float16)fabsf(gv[n4] * acc[n4][0] + bv[n4]);
                Ash[rq + 1][n] = (_Float16)fabsf(gv[n4] * acc[n4][1] + bv[n4]);
                Ash[rq + 2][n] = (_Float16)fabsf(gv[n4] * acc[n4][2] + bv[n4]);
                Ash[rq + 3][n] = (_Float16)fabsf(gv[n4] * acc[n4][3] + bv[n4]);
            }
        }
        __syncthreads();   // B2: activations ready

        if (t == T_ - 1) {
            // ---- final projection: out += A_tile @ dec_tile ----
            for (int idx = tid; idx < BT * DOUT; idx += THREADS) {
                const int r = idx / DOUT;
                const int d = idx % DOUT;
                float o = 0.f;
                #pragma unroll 8
                for (int n = 0; n < NT; ++n)
                    o += (float)Ash[r][n] * dec[(size_t)(n0 + n) * DOUT + d];
                atomicAdd(&out[(size_t)(b0 + r) * DOUT + d], o);
            }
            return;
        }

        // ---- decode (waves 0-3, full K=512) + u_{t+1} staging (waves 4-7) ----
        if (w < 4) {
            f32x4 d0 = (f32x4){0.f, 0.f, 0.f, 0.f};
            f32x4 d1 = (f32x4){0.f, 0.f, 0.f, 0.f};
            #pragma unroll
            for (int kt = 0; kt < 16; kt += 2) {
                const half8 a0 = *(const half8*)&Ash[m16][kt * 32 + q8];
                d0 = __builtin_amdgcn_mfma_f32_16x16x32_f16(a0, sdf[kt], d0, 0, 0, 0);
                const half8 a1 = *(const half8*)&Ash[m16][(kt + 1) * 32 + q8];
                d1 = __builtin_amdgcn_mfma_f32_16x16x32_f16(a1, sdf[kt + 1], d1, 0, 0, 0);
            }
            d0[0] += d1[0]; d0[1] += d1[1]; d0[2] += d1[2]; d0[3] += d1[3];
            // C/D: col = lane&15 -> state col 16w+m16; rows 0..7 in lanes 0..31
            if (l < 32) {
                const int rq = (l >> 4) << 2;
                const size_t slot = (size_t)(t & 1) * PSQ_ELEMS
                    + (((size_t)bt * NTILES + nt) * BT) * DS + 16 * w + m16;
                unsigned long long* pwF = psqF + slot;
                unsigned long long* pwS = psqS + slot;
                const unsigned long long tg = (unsigned long long)(unsigned)(t + 1) << 32;
                #pragma unroll
                for (int r = 0; r < 4; ++r) {
                    const unsigned long long val =
                        tg | (unsigned long long)__float_as_uint(d0[r]);
                    asm volatile("global_store_dwordx2 %0, %1, off sc0"
                                 :: "v"(pwF + (size_t)(rq + r) * DS), "v"(val)
                                 : "memory");
                    __hip_atomic_store(pwS + (size_t)(rq + r) * DS, val,
                                       __ATOMIC_RELAXED, __HIP_MEMORY_SCOPE_AGENT);
                }
            }
        } else if (l < 32) {
            // stage u_{t+1}: 4 waves x 32 lanes = 128 float4 loads
            const int idx = ((w - 4) << 5) + l;     // 0..127
            const int r = idx >> 4, c = (idx & 15) << 2;
            const float4 uv =
                *(const float4*)&seq[((size_t)(b0 + r) * T_ + (t + 1)) * DIN + c];
            _Float16* p = &xh[r][c];
            p[0] = (_Float16)uv.x; p[1] = (_Float16)uv.y;
            p[2] = (_Float16)uv.z; p[3] = (_Float16)uv.w;
        }
        __syncthreads();   // B3: decode reads of Ash done + u_{t+1} staged
        // no drain, no counter — tag rides with the data
    }
}

extern "C" void kernel_launch(void* const* d_in, const int* in_sizes, int n_in,
                              void* d_out, int out_size, void* d_ws, size_t ws_size,
                              hipStream_t stream) {
    const float* seq  = (const float*)d_in[0];
    const float* enc  = (const float*)d_in[1];
    const float* bias = (const float*)d_in[2];
    const float* gain = (const float*)d_in[3];
    const float* sd   = (const float*)d_in[4];
    const float* dec  = (const float*)d_in[5];
    float* out = (float*)d_out;
    float* ws  = (float*)d_ws;   // psqF (2MB) | psqS (2MB) | EtSw | SdSw

    pre_kernel<<<dim3(1024), dim3(256), 0, stream>>>(enc, sd, ws, out);

    unsigned long long* psqF = (unsigned long long*)ws;
    unsigned long long* psqS = (unsigned long long*)(ws + SLOW_OFF_F);
    const _Float16* EtSw = (const _Float16*)(ws + ETSW_OFF);
    const _Float16* SdSw = (const _Float16*)(ws + SDSW_OFF);

    persist_kernel<<<dim3(NWG), dim3(THREADS), 0, stream>>>(
        seq, EtSw, SdSw, bias, gain, dec, psqF, psqS, out);
}